// Round 6
// baseline (98.997 us; speedup 1.0000x reference)
//
#include <hip/hip_runtime.h>
#include <hip/hip_bf16.h>

using bf16 = __hip_bfloat16;
typedef __attribute__((ext_vector_type(8))) short short8;
typedef __attribute__((ext_vector_type(4))) float f32x4;

__device__ __constant__ int c_dil[8] = {1, 2, 4, 8, 1, 2, 4, 8};

__device__ inline void store1(float* p, float v) { *p = v; }
__device__ inline void store1(bf16* p, float v) { *p = __float2bfloat16(v); }

// async global->LDS, 16 B per lane; LDS dest must be wave-uniform base + lane*16
__device__ inline void gload_lds16(const void* g, void* l) {
    __builtin_amdgcn_global_load_lds(
        (const __attribute__((address_space(1))) unsigned int*)g,
        (__attribute__((address_space(3))) unsigned int*)l, 16, 0, 0);
}

template <int N> __device__ inline void vwait() {
    asm volatile("s_waitcnt vmcnt(%0)" :: "n"(N) : "memory");
}

// manual RNE f32->bf16
__device__ inline unsigned short f2bf(float f) {
    const unsigned u = __float_as_uint(f);
    return (unsigned short)((u + 0x7fffu + ((u >> 16) & 1u)) >> 16);
}
__device__ inline float bf2f(unsigned short h) { return __uint_as_float(((unsigned)h) << 16); }

// ---------------- fused convert: f32 -> bf16 ----------------
// mode 0: row = ld, plain;  mode 1: row = 1024, [hi|lo] (x);  mode 2: row = 1024, [hi|hi] (QK w)
__device__ inline void conv_block(const float* __restrict__ src, bf16* __restrict__ dst,
                                  int ld, int mode, int idx) {
    const float4 v = *reinterpret_cast<const float4*>(src + idx);
    const int r = idx >> 9, c = idx & 511;
    bf16* d = dst + (size_t)r * ld + c;
    const float vv[4] = {v.x, v.y, v.z, v.w};
    ushort4 hi, lo;
    unsigned short* hp = &hi.x; unsigned short* lp = &lo.x;
#pragma unroll
    for (int j = 0; j < 4; ++j) {
        hp[j] = f2bf(vv[j]);
        lp[j] = f2bf(vv[j] - bf2f(hp[j]));
    }
    *reinterpret_cast<ushort4*>(d) = hi;
    if (mode == 1) *reinterpret_cast<ushort4*>(d + 512) = lo;
    else if (mode == 2) *reinterpret_cast<ushort4*>(d + 512) = hi;
}

__global__ __launch_bounds__(256) void conv_all(
    const float* __restrict__ x,  const float* __restrict__ qw, const float* __restrict__ kw,
    const float* __restrict__ vw, const float* __restrict__ ow,
    const float* __restrict__ qb, const float* __restrict__ kb,
    bf16* A2, bf16* Wqk, bf16* Wv, bf16* Wo, float* bqk)
{
    const int b = blockIdx.x, t = threadIdx.x;
    if (b < 2048)       conv_block(x,  A2,                       1024, 1, (b * 256 + t) * 4);
    else if (b < 2304)  conv_block(qw, Wqk,                      1024, 2, ((b - 2048) * 256 + t) * 4);
    else if (b < 3584)  conv_block(kw, Wqk + (size_t)512 * 1024, 1024, 2, ((b - 2304) * 256 + t) * 4);
    else if (b < 4864)  conv_block(vw, Wv,                        512, 0, ((b - 3584) * 256 + t) * 4);
    else if (b < 5120)  conv_block(ow, Wo,                        512, 0, ((b - 4864) * 256 + t) * 4);
    else { const int i = (b - 5120) * 256 + t; bqk[i] = (i < 512) ? qb[i] : kb[i - 512]; }
}

// ---------------- MFMA GEMM, 128 x BN tile, BK=32, 4 waves ----------------
// 4-buffer LDS pipeline, prefetch depth 3, counted vmcnt (3 tiles stay in flight across
// raw s_barriers), setprio around the MFMA cluster. Source-swizzled staging keeps LDS
// reads 2-way max. Grid: 1D, XCD-chunked for L2 locality. Dual-target: col-tile bx < nx0
// -> target 0, else target 1 (fewer K-steps, hi half of A only).
template <int BN, typename TC>
__global__ __launch_bounds__(256) void gemm128(
    const bf16* __restrict__ A, int lda, int cw, int rpx,
    const bf16* __restrict__ W0, int ldw0, const float* __restrict__ b0,
    TC* __restrict__ C0, int ldc0, int nt0, int nx0,
    const bf16* __restrict__ W1, int ldw1, const float* __restrict__ b1,
    bf16* __restrict__ C1, int ldc1, int nt1)
{
    constexpr int NF = BN / 32;                  // per-wave N fragments
    constexpr int NLOAD = (BN == 128) ? 4 : 3;   // gload_lds per wave per stage
    __shared__ short As[4][128 * 32];
    __shared__ short Bs[4][BN * 32];

    const int tid = threadIdx.x, wid = tid >> 6, lane = tid & 63;

    // XCD-chunked mapping
    const int xcd = (int)blockIdx.x & 7;
    const int i   = (int)blockIdx.x >> 3;
    const int grp = rpx * cw;
    const int cc = i / grp, w2 = i % grp;
    const int rr = w2 / cw, c = w2 % cw;
    const int bx = cc * cw + c;
    const int by = xcd * rpx + rr;

    const int bm = by * 128;
    const bool t0 = bx < nx0;
    const int bn = (t0 ? bx : bx - nx0) * BN;
    const bf16* W      = t0 ? W0 : W1;
    const int   ldw    = t0 ? ldw0 : ldw1;
    const float* bias  = t0 ? b0 : b1;
    const int   nsteps = t0 ? nt0 : nt1;

    // staging source pointers (pre-swizzled word within each 64 B row-window)
    const int srow = lane >> 2;
    const int ssw  = (((lane & 3) ^ ((lane >> 3) & 3)) << 4);
    const char* pA0 = (const char*)A + (size_t)(bm + wid * 16 + srow) * lda * 2 + ssw;
    const char* pA1 = pA0 + (size_t)64 * lda * 2;
    const char* pB0 = (const char*)W + (size_t)(bn + wid * 16 + srow) * ldw * 2 + ssw;
    const char* pB1 = pB0 + (size_t)64 * ldw * 2;   // BN==128 only

    f32x4 acc[4][NF];
#pragma unroll
    for (int m = 0; m < 4; ++m)
#pragma unroll
        for (int n = 0; n < NF; ++n) acc[m][n] = f32x4{0.f, 0.f, 0.f, 0.f};

    // read offsets (XOR-unswizzled, per-thread constant)
    const int lr16 = lane & 15;
    const int wsw8 = (((lane >> 4) ^ ((lr16 >> 1) & 3)) << 3);
    const int wr = wid >> 1, wc = wid & 1;
    int offA[4], offB[NF];
#pragma unroll
    for (int m = 0; m < 4; ++m) offA[m] = (wr * 4 + m) * 512 + lr16 * 32 + wsw8;
#pragma unroll
    for (int n = 0; n < NF; ++n) offB[n] = (wc * NF + n) * 512 + lr16 * 32 + wsw8;

    auto stage = [&](int buf) {
        gload_lds16(pA0, (char*)As[buf] + wid * 1024);
        gload_lds16(pA1, (char*)As[buf] + (wid + 4) * 1024);
        gload_lds16(pB0, (char*)Bs[buf] + wid * 1024);
        if constexpr (BN == 128) gload_lds16(pB1, (char*)Bs[buf] + (wid + 4) * 1024);
        pA0 += 64; pA1 += 64; pB0 += 64;
        if constexpr (BN == 128) pB1 += 64;
    };

    stage(0);
    stage(1);
    stage(2);

    for (int s = 0; s < nsteps; ++s) {
        const int cur = s & 3;
        // issue tile s+3 into the buffer freed after step s-1; counted waits keep
        // tiles s+1..s+3 in flight across the barriers (T3/T4).
        if (s + 3 < nsteps) {
            stage((s + 3) & 3);
            vwait<3 * NLOAD>();
        } else if (s + 2 < nsteps) {
            vwait<2 * NLOAD>();
        } else if (s + 1 < nsteps) {
            vwait<NLOAD>();
        } else {
            vwait<0>();
        }
        __builtin_amdgcn_s_barrier();          // all waves' tile-s loads landed
        __builtin_amdgcn_sched_barrier(0);

        short8 af[4], bw[NF];
#pragma unroll
        for (int m = 0; m < 4; ++m)
            af[m] = *(const short8*)&As[cur][offA[m]];
#pragma unroll
        for (int n = 0; n < NF; ++n)
            bw[n] = *(const short8*)&Bs[cur][offB[n]];

        __builtin_amdgcn_s_setprio(1);         // T5: favor MFMA-entering waves
#pragma unroll
        for (int m = 0; m < 4; ++m)
#pragma unroll
            for (int n = 0; n < NF; ++n)
                acc[m][n] = __builtin_amdgcn_mfma_f32_16x16x32_bf16(af[m], bw[n], acc[m][n], 0, 0, 0);
        __builtin_amdgcn_s_setprio(0);

        __builtin_amdgcn_s_barrier();          // reads of buf `cur` done -> safe to restage next iter
        __builtin_amdgcn_sched_barrier(0);
    }

    // epilogue: C/D layout col=lane&15, row=(lane>>4)*4+reg
    const int r4 = (lane >> 4) * 4;
#pragma unroll
    for (int m = 0; m < 4; ++m) {
#pragma unroll
        for (int n = 0; n < NF; ++n) {
            const int col = bn + wc * (NF * 16) + n * 16 + lr16;
            const float bv = bias[col];
#pragma unroll
            for (int j = 0; j < 4; ++j) {
                const int row = bm + wr * 64 + m * 16 + r4 + j;
                const float v = acc[m][n][j] + bv;
                if (t0) store1(C0 + (size_t)row * ldc0 + col, v);
                else    store1(C1 + (size_t)row * ldc1 + col, v);
            }
        }
    }
}

// ---------------- local attention stitch ----------------
__global__ __launch_bounds__(256) void attn_k(
    const bf16* __restrict__ PQK, const bf16* __restrict__ PV, bf16* __restrict__ Aout)
{
    const int lane = threadIdx.x & 63;
    const int wave = threadIdx.x >> 6;
    const int task = blockIdx.x * 4 + wave;  // 0..32767
    const int h  = task & 7;
    const int bl = task >> 3;
    const int l  = bl & 2047;
    const int d  = c_dil[h];

    const float q = __bfloat162float(PQK[(size_t)bl * 3072 + h * 64 + lane]);

    float logits[5], vvals[5];
#pragma unroll
    for (int kk = 0; kk < 5; ++kk) {
        const int pos = l + (kk - 2) * d;
        const bool ok = (pos >= 0) && (pos < 2048);
        float kv = 0.f, vv = 0.f;
        if (ok) {
            const size_t rb = (size_t)(bl - l + pos);
            kv = __bfloat162float(PQK[rb * 3072 + 512 + (h * 5 + kk) * 64 + lane]);
            vv = __bfloat162float(PV[rb * 2560 + (h * 5 + kk) * 64 + lane]);
        }
        vvals[kk] = vv;
        float lg = q * kv;
#pragma unroll
        for (int s = 32; s; s >>= 1) lg += __shfl_xor(lg, s);
        logits[kk] = lg;  // OOB -> 0, matches reference (zero-padded content, zero bias)
    }

    float mx = logits[0];
#pragma unroll
    for (int kk = 1; kk < 5; ++kk) mx = fmaxf(mx, logits[kk]);
    float e[5], ssum = 0.f;
#pragma unroll
    for (int kk = 0; kk < 5; ++kk) { e[kk] = __expf(logits[kk] - mx); ssum += e[kk]; }
    float acc = 0.f;
#pragma unroll
    for (int kk = 0; kk < 5; ++kk) acc += e[kk] * vvals[kk];
    acc *= 0.125f / ssum;

    Aout[(size_t)bl * 512 + h * 64 + lane] = __float2bfloat16(acc);
}

// ---------------- launch ----------------
extern "C" void kernel_launch(void* const* d_in, const int* in_sizes, int n_in,
                              void* d_out, int out_size, void* d_ws, size_t ws_size,
                              hipStream_t stream)
{
    const float* x   = (const float*)d_in[0];
    const float* q_w = (const float*)d_in[1];
    const float* q_b = (const float*)d_in[2];
    const float* k_w = (const float*)d_in[3];
    const float* k_b = (const float*)d_in[4];
    const float* v_w = (const float*)d_in[5];
    const float* v_b = (const float*)d_in[6];
    const float* o_w = (const float*)d_in[7];
    const float* o_b = (const float*)d_in[8];
    float* out = (float*)d_out;

    const int M = 4096;

    // workspace: 8 + 6 + 2.5 + 0.5 + 0.012 + 24 + 20 = 61.0 MB
    char* p = (char*)d_ws;
    bf16* A2  = (bf16*)p;  p += (size_t)M * 1024 * 2;       // [x_hi | x_lo]
    bf16* Wqk = (bf16*)p;  p += (size_t)3072 * 1024 * 2;    // [w_hi | w_hi]
    bf16* Wv  = (bf16*)p;  p += (size_t)2560 * 512 * 2;
    bf16* Wo  = (bf16*)p;  p += (size_t)512 * 512 * 2;
    float* bqk = (float*)p; p += 3072 * 4;
    bf16* PQK = (bf16*)p;  p += (size_t)M * 3072 * 2;
    bf16* PV  = (bf16*)p;
    bf16* Aout = A2;  // A2 dead after the QKV GEMM; reuse for attention output

    dim3 blk(256);
    conv_all<<<dim3(5132), blk, 0, stream>>>(x, q_w, k_w, v_w, o_w, q_b, k_b,
                                             A2, Wqk, Wv, Wo, bqk);
    // fused QKV: col-tiles 0-23 -> PQK (K=1024 exact-x schedule), 24-43 -> PV (K=512, hi half)
    // grid 1408 = 8 XCD x 4 chunks x (4 rows x 11 cols)
    gemm128<128, bf16><<<dim3(1408), blk, 0, stream>>>(
        A2, 1024, /*cw*/11, /*rpx*/4,
        Wqk, 1024, bqk, PQK, 3072, 32, 24,
        Wv,  512,  v_b, PV,  2560, 16);
    attn_k<<<dim3(8192), blk, 0, stream>>>(PQK, PV, Aout);
    // grid 256 = 8 XCD x (4 rows x 8 cols)
    gemm128<64, float><<<dim3(256), blk, 0, stream>>>(
        Aout, 512, /*cw*/8, /*rpx*/4,
        Wo, 512, o_b, out, 512, 16, 8,
        Wo, 512, o_b, PQK, 512, 16);  // target-1 args unused (nx0 covers grid)
}